// Round 1
// baseline (14588.600 us; speedup 1.0000x reference)
//
#include <hip/hip_runtime.h>
#include <stdint.h>

#define BATCH 256
#define SEQT  512
#define HID   512
#define NROWS 32        // permuted gate rows per block per layer
#define K0STEPS 33      // layer0: K = 512 (h0) + 16 (u pad)
#define K1STEPS 64      // layer1: K = 1024 ([h0|h1])
#define W0S 536         // LDS row stride (ushorts): 528 data + 8 pad (odd # of 16B quads)
#define W1S 1032        // 1024 data + 8 pad (odd # of 16B quads)
#define HEXT 1040       // h_ext row: h0[512] | h1[512] | u[8]+zeros[8]

typedef __attribute__((ext_vector_type(8)))  __bf16 bf16x8;
typedef __attribute__((ext_vector_type(16))) float  f32x16;

__device__ __forceinline__ unsigned short f2bf(float x) {
  union { float f; unsigned u; } v; v.f = x;
  return (unsigned short)((v.u + 0x7FFFu + ((v.u >> 16) & 1u)) >> 16);  // RNE
}
__device__ __forceinline__ float bf2f(unsigned short h) {
  union { unsigned u; float f; } v; v.u = ((unsigned)h) << 16;
  return v.f;
}
__device__ __forceinline__ float sigm(float x)     { return 1.0f / (1.0f + __expf(-x)); }
__device__ __forceinline__ float tanhfast(float x) { return 2.0f / (1.0f + __expf(-2.0f * x)) - 1.0f; }

// Persistent 2-layer LSTM. 256 blocks (1/CU, forced by ~100KB LDS), 4 waves each.
// 4 independent batch-groups of 64 blocks; flag barrier per tick within group only.
// Wave w: layer = w>>1, batch N-tile = w&1. Block owns 32 permuted gate rows
// (= 8 hidden units x 4 gates, rows 4u+{i,f,g,o}) of BOTH layers; weights bf16 in LDS.
__global__ __launch_bounds__(256, 1) void lstm_persist(
    const float* __restrict__ u_seq,
    const float* __restrict__ w_ih_0, const float* __restrict__ w_hh_0,
    const float* __restrict__ b_ih_0, const float* __restrict__ b_hh_0,
    const float* __restrict__ w_ih_1, const float* __restrict__ w_hh_1,
    const float* __restrict__ b_ih_1, const float* __restrict__ b_hh_1,
    const float* __restrict__ fc_w0, const float* __restrict__ fc_b0,
    const float* __restrict__ fc_w1, const float* __restrict__ fc_b1,
    float* __restrict__ out, int* flags, unsigned short* hbuf)
{
  extern __shared__ unsigned short lds[];
  unsigned short* w0 = lds;                 // [32][536]
  unsigned short* w1 = lds + NROWS * W0S;   // [32][1032]

  const int bid = blockIdx.x;
  const int grp = bid >> 6;            // group 0..3 (64-batch tile)
  const int r   = bid & 63;            // rank in group -> owns rows [32r, 32r+32)
  const int batch0 = grp * 64;
  const int tid = threadIdx.x;
  const int wv  = tid >> 6;
  const int lane = tid & 63;
  const int lw  = wv >> 1;             // 0: layer0, 1: layer1
  const int nt  = wv & 1;              // batch N-tile (32 each)
  const int lrow = lane & 31;          // A row (perm gate row) / B col (batch in tile)
  const int kh   = lane >> 5;          // K half within MFMA step
  const int my_batch = batch0 + nt * 32 + lrow;
  const int rowbase = r * NROWS;

  // ---- stage weights fp32 -> bf16, gate-permuted (row = 4*unit + gate) ----
  for (int idx = tid; idx < NROWS * 528; idx += 256) {
    int pl = idx / 528, k = idx - pl * 528;
    int p = rowbase + pl;
    int orig = (p & 3) * HID + (p >> 2);          // gate*512 + unit
    float v = 0.0f;
    if (k < 512) v = w_hh_0[orig * HID + k];
    else if (k < 520) v = w_ih_0[orig * 8 + (k - 512)];   // u fold, zero-padded to 16
    w0[pl * W0S + k] = f2bf(v);
  }
  for (int idx = tid; idx < NROWS * 1024; idx += 256) {
    int pl = idx >> 10, k = idx & 1023;
    int p = rowbase + pl;
    int orig = (p & 3) * HID + (p >> 2);
    float v = (k < 512) ? w_ih_1[orig * HID + k] : w_hh_1[orig * HID + (k - 512)];
    w1[pl * W1S + k] = f2bf(v);
  }

  // ---- per-lane bias (b_ih + b_hh) for this wave's layer, in D-frag order ----
  float bias[16];
  {
    const float* bi = lw ? b_ih_1 : b_ih_0;
    const float* bh = lw ? b_hh_1 : b_hh_0;
#pragma unroll
    for (int rg = 0; rg < 16; ++rg) {
      int row = (rg & 3) + 8 * (rg >> 2) + 4 * kh;  // verified 32x32 D row mapping
      int p = rowbase + row;
      int orig = (p & 3) * HID + (p >> 2);
      bias[rg] = bi[orig] + bh[orig];
    }
  }

  // ---- zero own h_ext rows in both buffers, stage u_0 ----
  {
    unsigned short* row0 = hbuf + (size_t)(batch0 + r) * HEXT;
    unsigned short* row1 = hbuf + (size_t)(BATCH + batch0 + r) * HEXT;
    for (int k = tid; k < HEXT; k += 256) { row0[k] = 0; row1[k] = 0; }
    __syncthreads();
    if (tid < 8) row0[1024 + tid] = f2bf(u_seq[((size_t)(batch0 + r) * SEQT) * 8 + tid]);
  }

  // group-scope barrier: release store -> spin (relaxed agent loads hit coherence
  // point) -> acquire fence (L1/L2 inv for cross-XCD h visibility)
  auto groupbar = [&](int g) {
    __syncthreads();   // drains this block's vmem stores (vmcnt 0)
    if (tid == 0)
      __hip_atomic_store(&flags[bid], g, __ATOMIC_RELEASE, __HIP_MEMORY_SCOPE_AGENT);
    if (tid < 64) {
      int* fl = &flags[(grp << 6) + tid];
      while (__hip_atomic_load(fl, __ATOMIC_RELAXED, __HIP_MEMORY_SCOPE_AGENT) < g)
        __builtin_amdgcn_s_sleep(2);
      __builtin_amdgcn_fence(__ATOMIC_ACQUIRE, "agent");
    }
    __syncthreads();
  };

  int gen = 1;
  groupbar(gen++);

  float cc[4] = {0.f, 0.f, 0.f, 0.f};   // cell state, fp32, never leaves regs

  // tick tau: layer0 does step tau (tau<T), layer1 does step tau-1 (tau>=1).
  // reads hbuf[tau&1], writes hbuf[(tau+1)&1]; barrier makes double-buffer safe.
  for (int tau = 0; tau <= SEQT; ++tau) {
    const unsigned short* cur = hbuf + (size_t)((tau & 1) ? BATCH : 0) * HEXT;
    unsigned short*       nxt = hbuf + (size_t)((tau & 1) ? 0 : BATCH) * HEXT;
    const bool active = lw ? (tau >= 1) : (tau < SEQT);
    if (active) {
      f32x16 acc;
#pragma unroll
      for (int i = 0; i < 16; ++i) acc[i] = bias[i];
      const unsigned short* brow = cur + (size_t)my_batch * HEXT + kh * 8;
      if (lw == 0) {
        const unsigned short* arow = w0 + lrow * W0S + kh * 8;
#pragma unroll
        for (int s = 0; s < K0STEPS; ++s) {
          int bk = (s < 32) ? s * 16 : 1024;     // last step: u slot in h_ext
          bf16x8 a = *(const bf16x8*)(arow + s * 16);
          bf16x8 b = *(const bf16x8*)(brow + bk);
          acc = __builtin_amdgcn_mfma_f32_32x32x16_bf16(a, b, acc, 0, 0, 0);
        }
      } else {
        const unsigned short* arow = w1 + lrow * W1S + kh * 8;
#pragma unroll
        for (int s = 0; s < K1STEPS; ++s) {
          bf16x8 a = *(const bf16x8*)(arow + s * 16);
          bf16x8 b = *(const bf16x8*)(brow + s * 16);
          acc = __builtin_amdgcn_mfma_f32_32x32x16_bf16(a, b, acc, 0, 0, 0);
        }
      }
      // lane-local cell update: reg 4q+g = gate g of unit (2q + kh); batch = lane&31 col
      unsigned short* nrow = nxt + (size_t)my_batch * HEXT + lw * 512 + (r << 3) + kh;
#pragma unroll
      for (int q = 0; q < 4; ++q) {
        float ig = sigm(acc[4 * q + 0]);
        float fg = sigm(acc[4 * q + 1]);
        float gg = tanhfast(acc[4 * q + 2]);
        float og = sigm(acc[4 * q + 3]);
        float c = fg * cc[q] + ig * gg;
        cc[q] = c;
        nrow[2 * q] = f2bf(og * tanhfast(c));
      }
    }
    // stage u_{tau+1} (one batch row per block)
    if (tid < 8 && tau + 1 < SEQT) {
      nxt[(size_t)(batch0 + r) * HEXT + 1024 + tid] =
          f2bf(u_seq[((size_t)(batch0 + r) * SEQT + (tau + 1)) * 8 + tid]);
    }
    groupbar(gen++);
  }

  // ---- FC head (fp32): block bid handles batch row bid (within own group's tile) ----
  {
    float* hfc = (float*)lds;          // [256] (weights dead now)
    float* hTl = ((float*)lds) + 256;  // [512]
    const unsigned short* hT = hbuf + (size_t)(BATCH + bid) * HEXT + 512;  // h1_{T-1} in buf1
    for (int k = tid; k < 512; k += 256) hTl[k] = bf2f(hT[k]);
    __syncthreads();
    {
      float s = fc_b0[tid];
      const float4* wrow = (const float4*)(fc_w0 + (size_t)tid * 512);
#pragma unroll 4
      for (int k4 = 0; k4 < 128; ++k4) {
        float4 wq = wrow[k4];
        s += hTl[4 * k4 + 0] * wq.x + hTl[4 * k4 + 1] * wq.y +
             hTl[4 * k4 + 2] * wq.z + hTl[4 * k4 + 3] * wq.w;
      }
      hfc[tid] = tanhfast(s);
    }
    __syncthreads();
    if (tid < 64) {
#pragma unroll
      for (int kk = 0; kk < 2; ++kk) {
        float p = 0.f;
        for (int j = tid; j < 256; j += 64) p += hfc[j] * fc_w1[kk * 256 + j];
#pragma unroll
        for (int off = 32; off; off >>= 1) p += __shfl_down(p, off, 64);
        // out = (x+1)/2*(4.2-2.5)+2.5 = 0.85x + 3.35
        if (tid == 0) out[bid * 2 + kk] = p * 0.85f + (fc_b1[kk] * 0.85f + 3.35f);
      }
    }
  }
}

extern "C" void kernel_launch(void* const* d_in, const int* in_sizes, int n_in,
                              void* d_out, int out_size, void* d_ws, size_t ws_size,
                              hipStream_t stream) {
  const float* u_seq  = (const float*)d_in[0];
  const float* w_ih_0 = (const float*)d_in[1];
  const float* w_hh_0 = (const float*)d_in[2];
  const float* b_ih_0 = (const float*)d_in[3];
  const float* b_hh_0 = (const float*)d_in[4];
  const float* w_ih_1 = (const float*)d_in[5];
  const float* w_hh_1 = (const float*)d_in[6];
  const float* b_ih_1 = (const float*)d_in[7];
  const float* b_hh_1 = (const float*)d_in[8];
  const float* fc_w0  = (const float*)d_in[9];
  const float* fc_b0  = (const float*)d_in[10];
  const float* fc_w1  = (const float*)d_in[11];
  const float* fc_b1  = (const float*)d_in[12];
  float* out = (float*)d_out;

  // ws layout: [0,1KB): 256 barrier flags (0xAA poison is negative -> safe);
  //            [4KB, 4KB+1.04MB): double-buffered h_ext (bf16)
  int* flags = (int*)d_ws;
  unsigned short* hbuf = (unsigned short*)((char*)d_ws + 4096);

  size_t shmem = (size_t)(NROWS * W0S + NROWS * W1S) * sizeof(unsigned short);  // 100,352 B
  hipFuncSetAttribute((const void*)lstm_persist,
                      hipFuncAttributeMaxDynamicSharedMemorySize, (int)shmem);
  hipLaunchKernelGGL(lstm_persist, dim3(256), dim3(256), shmem, stream,
                     u_seq, w_ih_0, w_hh_0, b_ih_0, b_hh_0,
                     w_ih_1, w_hh_1, b_ih_1, b_hh_1,
                     fc_w0, fc_b0, fc_w1, fc_b1, out, flags, hbuf);
}

// Round 2
// 4290.826 us; speedup vs baseline: 3.4000x; 3.4000x over previous
//
#include <hip/hip_runtime.h>
#include <stdint.h>

#define HID   512
#define SEQT  512
#define NB    32            // batches per group
#define L1_STRIDE 257       // u64 per LDS B-row, layer1 (2056B, dword stride 514 % 32 == 2 -> 2-way, free)
#define L0_STRIDE 133       // u64 per LDS B-row, layer0 (1064B, dword stride 266 % 32 == 10 -> 2-way, free)
#define BUF1_U64  65536     // 256 batches * 256 u64 per h row

typedef __attribute__((ext_vector_type(8)))  __bf16 bf16x8;
typedef __attribute__((ext_vector_type(16))) float  f32x16;
typedef unsigned long long u64;

__device__ __forceinline__ unsigned short f2bf(float x) {
  union { float f; unsigned u; } v; v.f = x;
  return (unsigned short)((v.u + 0x7FFFu + ((v.u >> 16) & 1u)) >> 16);  // RNE
}
__device__ __forceinline__ float bf2f(unsigned short h) {
  union { unsigned u; float f; } v; v.u = ((unsigned)h) << 16;
  return v.f;
}
__device__ __forceinline__ float sigm(float x)     { return 1.0f / (1.0f + __expf(-x)); }
__device__ __forceinline__ float tanhfast(float x) { return 2.0f / (1.0f + __expf(-2.0f * x)) - 1.0f; }

// relaxed agent-scope ops: single global_load/store with sc1 (coherent at IF$),
// NO buffer_wbl2 / buffer_inv cache maintenance (that was Round 1's 28us/tick).
__device__ __forceinline__ u64 ld_agent(const u64* p) {
  return __hip_atomic_load(p, __ATOMIC_RELAXED, __HIP_MEMORY_SCOPE_AGENT);
}
__device__ __forceinline__ void st_agent(u64* p, u64 v) {
  __hip_atomic_store(p, v, __ATOMIC_RELAXED, __HIP_MEMORY_SCOPE_AGENT);
}

// 256 blocks = 8 groups x 32 blocks (16 layer0-blocks + 16 layer1-blocks), 32 batches/group.
// Block owns 32 hidden units (128 gate rows) of its layer; wave owns 8 units (32 gate rows).
// A-fragments (weights) live in REGISTERS (loop-invariant). Per tick: stage group h-tile
// into LDS via coherent 8B loads, 1 flag barrier per tick (no fences).
__global__ __launch_bounds__(256, 1) void lstm_persist(
    const float* __restrict__ u_seq,
    const float* __restrict__ w_ih_0, const float* __restrict__ w_hh_0,
    const float* __restrict__ b_ih_0, const float* __restrict__ b_hh_0,
    const float* __restrict__ w_ih_1, const float* __restrict__ w_hh_1,
    const float* __restrict__ b_ih_1, const float* __restrict__ b_hh_1,
    const float* __restrict__ fc_w0, const float* __restrict__ fc_b0,
    const float* __restrict__ fc_w1, const float* __restrict__ fc_b1,
    float* __restrict__ out, int* flags, u64* hbuf)
{
  extern __shared__ u64 smem[];    // B-tile staging (65792 B for L1 blocks)

  const int bid  = blockIdx.x;
  const int g    = bid >> 5;            // group 0..7
  const int rr   = bid & 31;            // rank in group
  const int isL1 = rr >> 4;             // 0: layer0 block, 1: layer1 block
  const int rl   = rr & 15;             // rank within layer
  const int tid  = threadIdx.x;
  const int wv   = tid >> 6;
  const int lane = tid & 63;
  const int lcol = lane & 31;           // A row (gate row) / B col (batch)
  const int kh   = lane >> 5;           // K-half within MFMA step
  const int batch0 = g * NB;

  const int unit_base = rl * 32 + wv * 8;       // 8 units per wave
  const int prow = unit_base * 4 + lcol;        // permuted gate row (4u+gate)
  const int orig = (prow & 3) * HID + (prow >> 2);

  auto groupbar = [&](int gen) {
    __syncthreads();   // drains each wave's vmcnt before s_barrier (sc1 stores acked at IF$)
    if (tid == 0)
      __hip_atomic_store(&flags[bid], gen, __ATOMIC_RELAXED, __HIP_MEMORY_SCOPE_AGENT);
    if (tid < 32) {
      const int* fl = flags + g * 32 + tid;
      while (__hip_atomic_load(fl, __ATOMIC_RELAXED, __HIP_MEMORY_SCOPE_AGENT) < gen)
        __builtin_amdgcn_s_sleep(1);
    }
    __syncthreads();
  };

  // ---- zero both h buffers (poisoned 0xAA by harness) ----
  {
    u64* p = hbuf + (size_t)bid * 512;
    st_agent(p + tid, 0);
    st_agent(p + tid + 256, 0);
  }
  int gen = 1;
  groupbar(gen++);

  if (isL1) {
    // ================= LAYER 1 BLOCK =================
    bf16x8 w[64];   // A-frags in registers: 64 x 4 VGPR = 256 VGPRs
    {
      const float* bih = w_ih_1 + (size_t)orig * HID;   // k<512: input = h0
      const float* bhh = w_hh_1 + (size_t)orig * HID;   // k>=512: recurrent h1
#pragma unroll
      for (int s = 0; s < 64; ++s) {
        int k = s * 16 + kh * 8;
        const float* src = (k < HID) ? (bih + k) : (bhh + (k - HID));
        float4 f0 = *(const float4*)src, f1 = *(const float4*)(src + 4);
        union { bf16x8 v; unsigned short h[8]; } u;
        u.h[0]=f2bf(f0.x); u.h[1]=f2bf(f0.y); u.h[2]=f2bf(f0.z); u.h[3]=f2bf(f0.w);
        u.h[4]=f2bf(f1.x); u.h[5]=f2bf(f1.y); u.h[6]=f2bf(f1.z); u.h[7]=f2bf(f1.w);
        w[s] = u.v;
      }
    }
    float bias[16];
#pragma unroll
    for (int rg = 0; rg < 16; ++rg) {
      int unit = unit_base + 2 * (rg >> 2) + kh;
      int gi = (rg & 3) * HID + unit;
      bias[rg] = b_ih_1[gi] + b_hh_1[gi];
    }
    float cc[4] = {0.f, 0.f, 0.f, 0.f};

    for (int tau = 0; tau <= SEQT; ++tau) {
      const u64* cur = hbuf + ((tau & 1) ? BUF1_U64 : 0);
      u64*       nxt = hbuf + ((tau & 1) ? 0 : BUF1_U64);
      if (tau >= 1) {
        // stage 32 full h rows (256 u64 each = [h0|h1]) into LDS; one row per wave per j
#pragma unroll
        for (int j = 0; j < 8; ++j) {
          int b = wv * 8 + j;
          const u64* gr = cur + (size_t)(batch0 + b) * 256;
          u64* lr = smem + (size_t)b * L1_STRIDE;
          u64 v0 = ld_agent(gr + lane);
          u64 v1 = ld_agent(gr + lane + 64);
          u64 v2 = ld_agent(gr + lane + 128);
          u64 v3 = ld_agent(gr + lane + 192);
          lr[lane] = v0; lr[lane + 64] = v1; lr[lane + 128] = v2; lr[lane + 192] = v3;
        }
        __syncthreads();
        f32x16 acc;
#pragma unroll
        for (int i = 0; i < 16; ++i) acc[i] = bias[i];
        const u64* br = smem + (size_t)lcol * L1_STRIDE + kh * 2;
#pragma unroll
        for (int s = 0; s < 64; ++s) {
          union { bf16x8 v; u64 q[2]; } bb;
          bb.q[0] = br[s * 4];
          bb.q[1] = br[s * 4 + 1];
          acc = __builtin_amdgcn_mfma_f32_32x32x16_bf16(w[s], bb.v, acc, 0, 0, 0);
        }
        // lane-local cell update; reg 4q+g = gate g of local unit 2q+kh
        float hv[4];
#pragma unroll
        for (int q = 0; q < 4; ++q) {
          float ig = sigm(acc[4 * q + 0]);
          float fg = sigm(acc[4 * q + 1]);
          float gg = tanhfast(acc[4 * q + 2]);
          float og = sigm(acc[4 * q + 3]);
          float c = fg * cc[q] + ig * gg;
          cc[q] = c;
          hv[q] = og * tanhfast(c);
        }
        unsigned own01 = (unsigned)f2bf(hv[0]) | ((unsigned)f2bf(hv[1]) << 16);
        unsigned own23 = (unsigned)f2bf(hv[2]) | ((unsigned)f2bf(hv[3]) << 16);
        unsigned p01 = (unsigned)__shfl_xor((int)own01, 32);
        unsigned p23 = (unsigned)__shfl_xor((int)own23, 32);
        if (kh == 0) {   // interleave even(own)/odd(partner) units -> 16B contiguous
          u64 q0 = ((u64)((own01 & 0xffffu) | ((p01 & 0xffffu) << 16)))
                 | (((u64)((own01 >> 16) | (p01 & 0xffff0000u))) << 32);
          u64 q1 = ((u64)((own23 & 0xffffu) | ((p23 & 0xffffu) << 16)))
                 | (((u64)((own23 >> 16) | (p23 & 0xffff0000u))) << 32);
          u64* orow = nxt + (size_t)(batch0 + lcol) * 256 + 128 + (unit_base >> 2);
          st_agent(orow, q0);
          st_agent(orow + 1, q1);
        }
      }
      groupbar(gen++);
    }
  } else {
    // ================= LAYER 0 BLOCK =================
    bf16x8 w[33];   // 132 VGPRs
    {
      const float* bhh = w_hh_0 + (size_t)orig * HID;
#pragma unroll
      for (int s = 0; s < 32; ++s) {
        int k = s * 16 + kh * 8;
        float4 f0 = *(const float4*)(bhh + k), f1 = *(const float4*)(bhh + k + 4);
        union { bf16x8 v; unsigned short h[8]; } u;
        u.h[0]=f2bf(f0.x); u.h[1]=f2bf(f0.y); u.h[2]=f2bf(f0.z); u.h[3]=f2bf(f0.w);
        u.h[4]=f2bf(f1.x); u.h[5]=f2bf(f1.y); u.h[6]=f2bf(f1.z); u.h[7]=f2bf(f1.w);
        w[s] = u.v;
      }
      { // step 32: kh=0 -> u columns (8), kh=1 -> zero pad
        union { bf16x8 v; unsigned short h[8]; } u;
        if (kh == 0) {
          const float* src = w_ih_0 + (size_t)orig * 8;
#pragma unroll
          for (int j = 0; j < 8; ++j) u.h[j] = f2bf(src[j]);
        } else {
#pragma unroll
          for (int j = 0; j < 8; ++j) u.h[j] = 0;
        }
        w[32] = u.v;
      }
    }
    float bias[16];
#pragma unroll
    for (int rg = 0; rg < 16; ++rg) {
      int unit = unit_base + 2 * (rg >> 2) + kh;
      int gi = (rg & 3) * HID + unit;
      bias[rg] = b_ih_0[gi] + b_hh_0[gi];
    }
    float cc[4] = {0.f, 0.f, 0.f, 0.f};

    // zero-pad region of LDS rows (shorts [520,528) = u64 [130,132)), written once
    if (tid < 64) smem[(size_t)(tid >> 1) * L0_STRIDE + 130 + (tid & 1)] = 0;

    for (int tau = 0; tau <= SEQT; ++tau) {
      const u64* cur = hbuf + ((tau & 1) ? BUF1_U64 : 0);
      u64*       nxt = hbuf + ((tau & 1) ? 0 : BUF1_U64);
      if (tau < SEQT) {
        // stage h0 (first 128 u64 of each row)
#pragma unroll
        for (int j = 0; j < 8; ++j) {
          int b = wv * 8 + j;
          const u64* gr = cur + (size_t)(batch0 + b) * 256;
          u64* lr = smem + (size_t)b * L0_STRIDE;
          u64 v0 = ld_agent(gr + lane);
          u64 v1 = ld_agent(gr + lane + 64);
          lr[lane] = v0; lr[lane + 64] = v1;
        }
        // stage u_tau (bf16) into shorts [512,520) of each row
        {
          int b = tid >> 3, i = tid & 7;
          unsigned short* srow = (unsigned short*)(smem + (size_t)b * L0_STRIDE);
          srow[512 + i] = f2bf(u_seq[((size_t)(batch0 + b) * SEQT + tau) * 8 + i]);
        }
        __syncthreads();
        f32x16 acc;
#pragma unroll
        for (int i = 0; i < 16; ++i) acc[i] = bias[i];
        const u64* br = smem + (size_t)lcol * L0_STRIDE + kh * 2;
#pragma unroll
        for (int s = 0; s < 33; ++s) {
          union { bf16x8 v; u64 q[2]; } bb;
          bb.q[0] = br[s * 4];
          bb.q[1] = br[s * 4 + 1];
          acc = __builtin_amdgcn_mfma_f32_32x32x16_bf16(w[s], bb.v, acc, 0, 0, 0);
        }
        float hv[4];
#pragma unroll
        for (int q = 0; q < 4; ++q) {
          float ig = sigm(acc[4 * q + 0]);
          float fg = sigm(acc[4 * q + 1]);
          float gg = tanhfast(acc[4 * q + 2]);
          float og = sigm(acc[4 * q + 3]);
          float c = fg * cc[q] + ig * gg;
          cc[q] = c;
          hv[q] = og * tanhfast(c);
        }
        unsigned own01 = (unsigned)f2bf(hv[0]) | ((unsigned)f2bf(hv[1]) << 16);
        unsigned own23 = (unsigned)f2bf(hv[2]) | ((unsigned)f2bf(hv[3]) << 16);
        unsigned p01 = (unsigned)__shfl_xor((int)own01, 32);
        unsigned p23 = (unsigned)__shfl_xor((int)own23, 32);
        if (kh == 0) {
          u64 q0 = ((u64)((own01 & 0xffffu) | ((p01 & 0xffffu) << 16)))
                 | (((u64)((own01 >> 16) | (p01 & 0xffff0000u))) << 32);
          u64 q1 = ((u64)((own23 & 0xffffu) | ((p23 & 0xffffu) << 16)))
                 | (((u64)((own23 >> 16) | (p23 & 0xffff0000u))) << 32);
          u64* orow = nxt + (size_t)(batch0 + lcol) * 256 + (unit_base >> 2);
          st_agent(orow, q0);
          st_agent(orow + 1, q1);
        }
      }
      groupbar(gen++);
    }
  }

  // ---- FC head (fp32): block bid handles batch bid (within its own group) ----
  {
    float* hT  = (float*)smem;          // [512]
    float* hfc = ((float*)smem) + 512;  // [256]
    const u64* hrow = hbuf + BUF1_U64 + (size_t)bid * 256 + 128;  // h1_{T-1} lives in buf1
    if (tid < 128) {
      u64 v = ld_agent(hrow + tid);
      const unsigned short* s4 = (const unsigned short*)&v;
      hT[tid * 4 + 0] = bf2f(s4[0]);
      hT[tid * 4 + 1] = bf2f(s4[1]);
      hT[tid * 4 + 2] = bf2f(s4[2]);
      hT[tid * 4 + 3] = bf2f(s4[3]);
    }
    __syncthreads();
    {
      float s = fc_b0[tid];
      const float4* wrow = (const float4*)(fc_w0 + (size_t)tid * HID);
#pragma unroll 4
      for (int k4 = 0; k4 < 128; ++k4) {
        float4 wq = wrow[k4];
        s += hT[4 * k4 + 0] * wq.x + hT[4 * k4 + 1] * wq.y +
             hT[4 * k4 + 2] * wq.z + hT[4 * k4 + 3] * wq.w;
      }
      hfc[tid] = tanhfast(s);
    }
    __syncthreads();
    if (tid < 64) {
#pragma unroll
      for (int kk = 0; kk < 2; ++kk) {
        float p = 0.f;
        for (int j = tid; j < 256; j += 64) p += hfc[j] * fc_w1[kk * 256 + j];
#pragma unroll
        for (int off = 32; off; off >>= 1) p += __shfl_down(p, off, 64);
        if (tid == 0) out[bid * 2 + kk] = p * 0.85f + (fc_b1[kk] * 0.85f + 3.35f);
      }
    }
  }
}

extern "C" void kernel_launch(void* const* d_in, const int* in_sizes, int n_in,
                              void* d_out, int out_size, void* d_ws, size_t ws_size,
                              hipStream_t stream) {
  const float* u_seq  = (const float*)d_in[0];
  const float* w_ih_0 = (const float*)d_in[1];
  const float* w_hh_0 = (const float*)d_in[2];
  const float* b_ih_0 = (const float*)d_in[3];
  const float* b_hh_0 = (const float*)d_in[4];
  const float* w_ih_1 = (const float*)d_in[5];
  const float* w_hh_1 = (const float*)d_in[6];
  const float* b_ih_1 = (const float*)d_in[7];
  const float* b_hh_1 = (const float*)d_in[8];
  const float* fc_w0  = (const float*)d_in[9];
  const float* fc_b0  = (const float*)d_in[10];
  const float* fc_w1  = (const float*)d_in[11];
  const float* fc_b1  = (const float*)d_in[12];
  float* out = (float*)d_out;

  // ws: [0,1KB) flags (0xAA poison is negative -> safe); [4KB, 4KB+1MB) double-buffered h
  int* flags = (int*)d_ws;
  u64* hbuf  = (u64*)((char*)d_ws + 4096);

  size_t shmem = (size_t)NB * L1_STRIDE * sizeof(u64);  // 65792 B
  hipFuncSetAttribute((const void*)lstm_persist,
                      hipFuncAttributeMaxDynamicSharedMemorySize, (int)shmem);
  hipLaunchKernelGGL(lstm_persist, dim3(256), dim3(256), shmem, stream,
                     u_seq, w_ih_0, w_hh_0, b_ih_0, b_hh_0,
                     w_ih_1, w_hh_1, b_ih_1, b_hh_1,
                     fc_w0, fc_b0, fc_w1, fc_b1, out, flags, hbuf);
}

// Round 3
// 2495.284 us; speedup vs baseline: 5.8465x; 1.7196x over previous
//
#include <hip/hip_runtime.h>
#include <stdint.h>

#define HID   512
#define SEQT  512
#define NB    32            // batches per group
#define L1_RB 2064          // LDS row stride B, layer1: 2048 data + 16 pad (516 dw = 4 mod 32 -> 2-way in-phase, ~free)
#define L0_RB 1072          // LDS row stride B, layer0: 1024 h0 + 16 u + 16 zeros + 16 pad (268 dw = 12 mod 32 -> 2-way)
#define BUF1_U64 65536      // 256 rows * 256 u64 per h buffer
#define FPAD 16             // flags padded to 64B (16 ints)

typedef __attribute__((ext_vector_type(8)))  __bf16 bf16x8;
typedef __attribute__((ext_vector_type(16))) float  f32x16;
typedef unsigned long long u64;

__device__ __forceinline__ unsigned short f2bf(float x) {
  union { float f; unsigned u; } v; v.f = x;
  return (unsigned short)((v.u + 0x7FFFu + ((v.u >> 16) & 1u)) >> 16);  // RNE
}
__device__ __forceinline__ float bf2f(unsigned short h) {
  union { unsigned u; float f; } v; v.u = ((unsigned)h) << 16;
  return v.f;
}
__device__ __forceinline__ float sigm(float x)     { return 1.0f / (1.0f + __expf(-x)); }
__device__ __forceinline__ float tanhfast(float x) { return 2.0f / (1.0f + __expf(-2.0f * x)) - 1.0f; }

__device__ __forceinline__ u64 ld_agent(const u64* p) {
  return __hip_atomic_load(p, __ATOMIC_RELAXED, __HIP_MEMORY_SCOPE_AGENT);
}
__device__ __forceinline__ void st_agent(u64* p, u64 v) {
  __hip_atomic_store(p, v, __ATOMIC_RELAXED, __HIP_MEMORY_SCOPE_AGENT);
}

// async global->LDS DMA, 16B/lane, cpol sc0|sc1 (bit0|bit4 = 0x11): bypass L1+L2,
// read at the IF$ coherence point. No VGPR round trip -> fully vmcnt-pipelined.
__device__ __forceinline__ void dma16(const void* g, void* l) {
  __builtin_amdgcn_global_load_lds((const unsigned int*)g, (unsigned int*)l, 16, 0, 0x11);
}

// 256 blocks = 8 groups x 32 (16 layer0 + 16 layer1), 32 batches/group.
// Weights in registers; per tick: DMA-stage group h-tile to LDS, MFMA (dual acc
// chains), lane-local cell update, sc1 h-store, 1 padded-flag barrier per tick.
__global__ __launch_bounds__(256, 1) void lstm_persist(
    const float* __restrict__ u_seq,
    const float* __restrict__ w_ih_0, const float* __restrict__ w_hh_0,
    const float* __restrict__ b_ih_0, const float* __restrict__ b_hh_0,
    const float* __restrict__ w_ih_1, const float* __restrict__ w_hh_1,
    const float* __restrict__ b_ih_1, const float* __restrict__ b_hh_1,
    const float* __restrict__ fc_w0, const float* __restrict__ fc_b0,
    const float* __restrict__ fc_w1, const float* __restrict__ fc_b1,
    float* __restrict__ out, int* flags, u64* hbuf)
{
  extern __shared__ char smemc[];    // B-tile staging (66048 B for L1 blocks)

  const int bid  = blockIdx.x;
  const int g    = bid >> 5;            // group 0..7
  const int rr   = bid & 31;            // rank in group
  const int isL1 = rr >> 4;
  const int rl   = rr & 15;             // rank within layer
  const int tid  = threadIdx.x;
  const int wv   = tid >> 6;
  const int lane = tid & 63;
  const int lcol = lane & 31;           // A row (gate row) / B col (batch)
  const int kh   = lane >> 5;           // K-half within MFMA step
  const int batch0 = g * NB;

  const int unit_base = rl * 32 + wv * 8;       // 8 units per wave
  const int prow = unit_base * 4 + lcol;        // permuted gate row (4u+gate)
  const int orig = (prow & 3) * HID + (prow >> 2);

  auto groupbar = [&](int gen) {
    __syncthreads();   // drains vmcnt (h-stores acked at IF$) before flag store
    if (tid == 0)
      __hip_atomic_store(&flags[bid * FPAD], gen, __ATOMIC_RELAXED, __HIP_MEMORY_SCOPE_AGENT);
    if (tid < 32) {
      const int* fl = flags + (g * 32 + tid) * FPAD;
      while (__hip_atomic_load(fl, __ATOMIC_RELAXED, __HIP_MEMORY_SCOPE_AGENT) < gen)
        __builtin_amdgcn_s_sleep(1);
    }
    __syncthreads();
  };

  // ---- zero both h buffers (ws poisoned 0xAA) ----
  {
    u64* p = hbuf + (size_t)bid * 512;
    st_agent(p + tid, 0);
    st_agent(p + tid + 256, 0);
  }
  int gen = 1;
  groupbar(gen++);

  if (isL1) {
    // ================= LAYER 1 BLOCK =================
    bf16x8 w[64];   // A-frags resident: 256 regs (unified VGPR/AGPR file, 1 wave/SIMD)
    {
      const float* bih = w_ih_1 + (size_t)orig * HID;   // k<512: input = h0
      const float* bhh = w_hh_1 + (size_t)orig * HID;   // k>=512: recurrent h1
#pragma unroll
      for (int s = 0; s < 64; ++s) {
        int k = s * 16 + kh * 8;
        const float* src = (k < HID) ? (bih + k) : (bhh + (k - HID));
        float4 f0 = *(const float4*)src, f1 = *(const float4*)(src + 4);
        union { bf16x8 v; unsigned short h[8]; } u;
        u.h[0]=f2bf(f0.x); u.h[1]=f2bf(f0.y); u.h[2]=f2bf(f0.z); u.h[3]=f2bf(f0.w);
        u.h[4]=f2bf(f1.x); u.h[5]=f2bf(f1.y); u.h[6]=f2bf(f1.z); u.h[7]=f2bf(f1.w);
        w[s] = u.v;
      }
    }
    float bias[16];
#pragma unroll
    for (int rg = 0; rg < 16; ++rg) {
      int unit = unit_base + 2 * (rg >> 2) + kh;
      int gi = (rg & 3) * HID + unit;
      bias[rg] = b_ih_1[gi] + b_hh_1[gi];
    }
    float cc[4] = {0.f, 0.f, 0.f, 0.f};

    for (int tau = 0; tau <= SEQT; ++tau) {
      const char* curb = (const char*)(hbuf + ((tau & 1) ? BUF1_U64 : 0));
      u64*        nxt  = hbuf + ((tau & 1) ? 0 : BUF1_U64);
      if (tau >= 1) {
        // DMA-stage 32 rows x 2KB; wave wv handles rows wv*8..wv*8+7, 2 chunks each
#pragma unroll
        for (int j = 0; j < 8; ++j) {
          int b = wv * 8 + j;
          const char* gr = curb + ((size_t)(batch0 + b) << 11) + lane * 16;
          char* lr = smemc + b * L1_RB;
          dma16(gr, lr);
          dma16(gr + 1024, lr + 1024);
        }
        __syncthreads();
        f32x16 a0, a1;
#pragma unroll
        for (int i = 0; i < 16; ++i) { a0[i] = bias[i]; a1[i] = 0.f; }
        const char* brow = smemc + lcol * L1_RB + kh * 16;
#pragma unroll
        for (int s = 0; s < 64; s += 2) {
          bf16x8 b0 = *(const bf16x8*)(brow + s * 32);
          bf16x8 b1 = *(const bf16x8*)(brow + s * 32 + 32);
          a0 = __builtin_amdgcn_mfma_f32_32x32x16_bf16(w[s],     b0, a0, 0, 0, 0);
          a1 = __builtin_amdgcn_mfma_f32_32x32x16_bf16(w[s + 1], b1, a1, 0, 0, 0);
        }
        float hv[4];
#pragma unroll
        for (int q = 0; q < 4; ++q) {
          float ig = sigm(a0[4 * q + 0] + a1[4 * q + 0]);
          float fg = sigm(a0[4 * q + 1] + a1[4 * q + 1]);
          float gg = tanhfast(a0[4 * q + 2] + a1[4 * q + 2]);
          float og = sigm(a0[4 * q + 3] + a1[4 * q + 3]);
          float c = fg * cc[q] + ig * gg;
          cc[q] = c;
          hv[q] = og * tanhfast(c);
        }
        unsigned own01 = (unsigned)f2bf(hv[0]) | ((unsigned)f2bf(hv[1]) << 16);
        unsigned own23 = (unsigned)f2bf(hv[2]) | ((unsigned)f2bf(hv[3]) << 16);
        unsigned p01 = (unsigned)__shfl_xor((int)own01, 32);
        unsigned p23 = (unsigned)__shfl_xor((int)own23, 32);
        if (kh == 0) {   // interleave even(own)/odd(partner) units -> 16B contiguous
          u64 q0 = ((u64)((own01 & 0xffffu) | ((p01 & 0xffffu) << 16)))
                 | (((u64)((own01 >> 16) | (p01 & 0xffff0000u))) << 32);
          u64 q1 = ((u64)((own23 & 0xffffu) | ((p23 & 0xffffu) << 16)))
                 | (((u64)((own23 >> 16) | (p23 & 0xffff0000u))) << 32);
          u64* orow = nxt + (size_t)(batch0 + lcol) * 256 + 128 + (unit_base >> 2);
          st_agent(orow, q0);
          st_agent(orow + 1, q1);
        }
      }
      groupbar(gen++);
    }
  } else {
    // ================= LAYER 0 BLOCK =================
    bf16x8 w[33];
    {
      const float* bhh = w_hh_0 + (size_t)orig * HID;
#pragma unroll
      for (int s = 0; s < 32; ++s) {
        int k = s * 16 + kh * 8;
        float4 f0 = *(const float4*)(bhh + k), f1 = *(const float4*)(bhh + k + 4);
        union { bf16x8 v; unsigned short h[8]; } u;
        u.h[0]=f2bf(f0.x); u.h[1]=f2bf(f0.y); u.h[2]=f2bf(f0.z); u.h[3]=f2bf(f0.w);
        u.h[4]=f2bf(f1.x); u.h[5]=f2bf(f1.y); u.h[6]=f2bf(f1.z); u.h[7]=f2bf(f1.w);
        w[s] = u.v;
      }
      { // step 32: kh=0 -> u columns, kh=1 -> zeros (row pad region)
        union { bf16x8 v; unsigned short h[8]; } u;
        if (kh == 0) {
          const float* src = w_ih_0 + (size_t)orig * 8;
#pragma unroll
          for (int j = 0; j < 8; ++j) u.h[j] = f2bf(src[j]);
        } else {
#pragma unroll
          for (int j = 0; j < 8; ++j) u.h[j] = 0;
        }
        w[32] = u.v;
      }
    }
    float bias[16];
#pragma unroll
    for (int rg = 0; rg < 16; ++rg) {
      int unit = unit_base + 2 * (rg >> 2) + kh;
      int gi = (rg & 3) * HID + unit;
      bias[rg] = b_ih_0[gi] + b_hh_0[gi];
    }
    float cc[4] = {0.f, 0.f, 0.f, 0.f};

    // zeros for kh=1 of MFMA step 32: row bytes [1040,1056), written once
    if (tid < 64) *(u64*)(smemc + (tid >> 1) * L0_RB + 1040 + (tid & 1) * 8) = 0;

    for (int tau = 0; tau <= SEQT; ++tau) {
      const char* curb = (const char*)(hbuf + ((tau & 1) ? BUF1_U64 : 0));
      u64*        nxt  = hbuf + ((tau & 1) ? 0 : BUF1_U64);
      if (tau < SEQT) {
#pragma unroll
        for (int j = 0; j < 8; ++j) {
          int b = wv * 8 + j;
          const char* gr = curb + ((size_t)(batch0 + b) << 11) + lane * 16;
          dma16(gr, smemc + b * L0_RB);   // h0 half only (1KB)
        }
        { // stage u_tau into row bytes [1024,1040)
          int b = tid >> 3, i = tid & 7;
          ((unsigned short*)(smemc + b * L0_RB))[512 + i] =
              f2bf(u_seq[((size_t)(batch0 + b) * SEQT + tau) * 8 + i]);
        }
        __syncthreads();
        f32x16 a0, a1;
#pragma unroll
        for (int i = 0; i < 16; ++i) { a0[i] = bias[i]; a1[i] = 0.f; }
        const char* brow = smemc + lcol * L0_RB + kh * 16;
#pragma unroll
        for (int s = 0; s < 32; s += 2) {
          bf16x8 b0 = *(const bf16x8*)(brow + s * 32);
          bf16x8 b1 = *(const bf16x8*)(brow + s * 32 + 32);
          a0 = __builtin_amdgcn_mfma_f32_32x32x16_bf16(w[s],     b0, a0, 0, 0, 0);
          a1 = __builtin_amdgcn_mfma_f32_32x32x16_bf16(w[s + 1], b1, a1, 0, 0, 0);
        }
        { // step 32: u fold (kh=0) / zeros (kh=1) at row offset 32*32
          bf16x8 b2 = *(const bf16x8*)(brow + 32 * 32);
          a0 = __builtin_amdgcn_mfma_f32_32x32x16_bf16(w[32], b2, a0, 0, 0, 0);
        }
        float hv[4];
#pragma unroll
        for (int q = 0; q < 4; ++q) {
          float ig = sigm(a0[4 * q + 0] + a1[4 * q + 0]);
          float fg = sigm(a0[4 * q + 1] + a1[4 * q + 1]);
          float gg = tanhfast(a0[4 * q + 2] + a1[4 * q + 2]);
          float og = sigm(a0[4 * q + 3] + a1[4 * q + 3]);
          float c = fg * cc[q] + ig * gg;
          cc[q] = c;
          hv[q] = og * tanhfast(c);
        }
        unsigned own01 = (unsigned)f2bf(hv[0]) | ((unsigned)f2bf(hv[1]) << 16);
        unsigned own23 = (unsigned)f2bf(hv[2]) | ((unsigned)f2bf(hv[3]) << 16);
        unsigned p01 = (unsigned)__shfl_xor((int)own01, 32);
        unsigned p23 = (unsigned)__shfl_xor((int)own23, 32);
        if (kh == 0) {
          u64 q0 = ((u64)((own01 & 0xffffu) | ((p01 & 0xffffu) << 16)))
                 | (((u64)((own01 >> 16) | (p01 & 0xffff0000u))) << 32);
          u64 q1 = ((u64)((own23 & 0xffffu) | ((p23 & 0xffffu) << 16)))
                 | (((u64)((own23 >> 16) | (p23 & 0xffff0000u))) << 32);
          u64* orow = nxt + (size_t)(batch0 + lcol) * 256 + (unit_base >> 2);
          st_agent(orow, q0);
          st_agent(orow + 1, q1);
        }
      }
      groupbar(gen++);
    }
  }

  // ---- FC head (fp32): block bid handles batch bid ----
  {
    float* hT  = (float*)smemc;          // [512]
    float* hfc = ((float*)smemc) + 512;  // [256]
    const u64* hrow = hbuf + BUF1_U64 + (size_t)bid * 256 + 128;  // h1_{T-1} in buf1
    if (tid < 128) {
      u64 v = ld_agent(hrow + tid);
      const unsigned short* s4 = (const unsigned short*)&v;
      hT[tid * 4 + 0] = bf2f(s4[0]);
      hT[tid * 4 + 1] = bf2f(s4[1]);
      hT[tid * 4 + 2] = bf2f(s4[2]);
      hT[tid * 4 + 3] = bf2f(s4[3]);
    }
    __syncthreads();
    {
      float s = fc_b0[tid];
      const float4* wrow = (const float4*)(fc_w0 + (size_t)tid * HID);
#pragma unroll 4
      for (int k4 = 0; k4 < 128; ++k4) {
        float4 wq = wrow[k4];
        s += hT[4 * k4 + 0] * wq.x + hT[4 * k4 + 1] * wq.y +
             hT[4 * k4 + 2] * wq.z + hT[4 * k4 + 3] * wq.w;
      }
      hfc[tid] = tanhfast(s);
    }
    __syncthreads();
    if (tid < 64) {
#pragma unroll
      for (int kk = 0; kk < 2; ++kk) {
        float p = 0.f;
        for (int j = tid; j < 256; j += 64) p += hfc[j] * fc_w1[kk * 256 + j];
#pragma unroll
        for (int off = 32; off; off >>= 1) p += __shfl_down(p, off, 64);
        if (tid == 0) out[bid * 2 + kk] = p * 0.85f + (fc_b1[kk] * 0.85f + 3.35f);
      }
    }
  }
}

extern "C" void kernel_launch(void* const* d_in, const int* in_sizes, int n_in,
                              void* d_out, int out_size, void* d_ws, size_t ws_size,
                              hipStream_t stream) {
  const float* u_seq  = (const float*)d_in[0];
  const float* w_ih_0 = (const float*)d_in[1];
  const float* w_hh_0 = (const float*)d_in[2];
  const float* b_ih_0 = (const float*)d_in[3];
  const float* b_hh_0 = (const float*)d_in[4];
  const float* w_ih_1 = (const float*)d_in[5];
  const float* w_hh_1 = (const float*)d_in[6];
  const float* b_ih_1 = (const float*)d_in[7];
  const float* b_hh_1 = (const float*)d_in[8];
  const float* fc_w0  = (const float*)d_in[9];
  const float* fc_b0  = (const float*)d_in[10];
  const float* fc_w1  = (const float*)d_in[11];
  const float* fc_b1  = (const float*)d_in[12];
  float* out = (float*)d_out;

  // ws: [0,16KB) 64B-padded flags (0xAA poison is negative -> safe);
  //     [16KB, 16KB+1MB) double-buffered h (bf16, 2KB/row)
  int* flags = (int*)d_ws;
  u64* hbuf  = (u64*)((char*)d_ws + 16384);

  size_t shmem = (size_t)NB * L1_RB;  // 66048 B
  hipFuncSetAttribute((const void*)lstm_persist,
                      hipFuncAttributeMaxDynamicSharedMemorySize, (int)shmem);
  hipLaunchKernelGGL(lstm_persist, dim3(256), dim3(256), shmem, stream,
                     u_seq, w_ih_0, w_hh_0, b_ih_0, b_hh_0,
                     w_ih_1, w_hh_1, b_ih_1, b_hh_1,
                     fc_w0, fc_b0, fc_w1, fc_b1, out, flags, hbuf);
}